// Round 2
// baseline (244.324 us; speedup 1.0000x reference)
//
#include <hip/hip_runtime.h>
#include <hip/hip_bf16.h>

#define K_CLS 20
#define HIN 480
#define WIN 640
#define NPIX (HIN * WIN)
#define C_ 512
#define H_ 30
#define W_ 40
#define NB_ 5
#define CNT_THRESH 10000
// out layout (fp32): pool_x[2048], NB, N, x_cropped[6*4*512*30*40]
#define XCROP_ELEMS (6 * 4 * C_ * H_ * W_)
#define ELEMS_PER_SN (C_ * H_ * W_)            // 614400 = one (s,n) slice
#define OUT_TOTAL (2050 + XCROP_ELEMS)

#define NBLK_STATS 300                 // NPIX/4/256 exactly
#define NODE_OFF (NBLK_STATS * 100)    // ws int offset of the 5 node boxes

// out_k geometry: 8 elems/thread, 256 thr/block -> 2048 elems/block.
// 614400 % 2048 == 0  -> sn (and box b) is uniform per block;
// 40 % 8 == 0         -> a thread's 8 elems never cross a row;
// 1200 % 8 == 0       -> never cross a channel.
#define OUT_TPB 256
#define OUT_EPT 8
#define OUT_BLK_ELEMS (OUT_TPB * OUT_EPT)               // 2048
#define BLKS_PER_SN (ELEMS_PER_SN / OUT_BLK_ELEMS)      // 300
#define OUT_BLOCKS (24 * BLKS_PER_SN)                   // 7200

// ws int layout: [block][cnt20|mnx20|mny20|mxx20|mxy20] * 300, then boxes[5*4]

__global__ void stats_k(const float* __restrict__ seg, int* __restrict__ ws) {
    __shared__ int s_cnt[K_CLS], s_mnx[K_CLS], s_mny[K_CLS], s_mxx[K_CLS], s_mxy[K_CLS];
    int t = threadIdx.x;
    if (t < K_CLS) { s_cnt[t] = 0; s_mnx[t] = WIN; s_mny[t] = HIN; s_mxx[t] = -1; s_mxy[t] = -1; }
    __syncthreads();

    int p = blockIdx.x * blockDim.x + t;                 // quad-pixel index, 0..76799
    const float4* base = (const float4*)(seg + (size_t)3 * K_CLS * NPIX) + p;
    float4 v = base[0];
    float b0 = v.x, b1 = v.y, b2 = v.z, b3 = v.w;
    int k0 = 0, k1 = 0, k2 = 0, k3 = 0;
    #pragma unroll
    for (int k = 1; k < K_CLS; k++) {                    // strict > : np.argmax tie-break
        float4 u = base[(size_t)k * (NPIX / 4)];
        if (u.x > b0) { b0 = u.x; k0 = k; }
        if (u.y > b1) { b1 = u.y; k1 = k; }
        if (u.z > b2) { b2 = u.z; k2 = k; }
        if (u.w > b3) { b3 = u.w; k3 = k; }
    }
    int x = (p * 4) % WIN, y = (p * 4) / WIN;            // quad never wraps a row (640%4==0)
    if (k0 == k1 && k1 == k2 && k2 == k3) {              // common case: uniform class
        atomicAdd(&s_cnt[k0], 4);
        atomicMin(&s_mnx[k0], x);     atomicMax(&s_mxx[k0], x + 3);
        atomicMin(&s_mny[k0], y);     atomicMax(&s_mxy[k0], y);
    } else {
        int ks[4] = {k0, k1, k2, k3};
        #pragma unroll
        for (int i = 0; i < 4; i++) {
            atomicAdd(&s_cnt[ks[i]], 1);
            atomicMin(&s_mnx[ks[i]], x + i);  atomicMax(&s_mxx[ks[i]], x + i);
            atomicMin(&s_mny[ks[i]], y);      atomicMax(&s_mxy[ks[i]], y);
        }
    }
    __syncthreads();
    if (t < 100) {                                       // per-block partial, plain store
        int a = t / 20, c = t % 20;
        int val = (a == 0) ? s_cnt[c] : (a == 1) ? s_mnx[c] : (a == 2) ? s_mny[c]
                : (a == 3) ? s_mxx[c] : s_mxy[c];
        ws[blockIdx.x * 100 + t] = val;
    }
}

// Parallel reduce 300 partial records -> final stats -> boxes.
// Also copies the 2050-float header (pool_x, NB, N) so out_k's mapping
// is purely the 8-aligned x_cropped region (no per-thread header branch).
__global__ void plan_k(int* __restrict__ ws, const float* __restrict__ pool_x,
                       float* __restrict__ out) {
    __shared__ int part[10][100];
    __shared__ int st[100];
    int t = threadIdx.x;                 // 0..1023

    // header: 2048 floats of pool_x as 1024 float2, then {NB, N}
    ((float2*)out)[t] = ((const float2*)pool_x)[t];
    if (t == 0) { out[2048] = 5.0f; out[2049] = 4.0f; }

    if (t < 1000) {
        int c = t % 100, chunk = t / 100;
        int a = c / 20;
        int acc = (a == 0) ? 0 : (a == 1) ? WIN : (a == 2) ? HIN : -1;
        #pragma unroll
        for (int i = 0; i < 30; i++) {
            int v = ws[(chunk * 30 + i) * 100 + c];
            if (a == 0)      acc += v;
            else if (a <= 2) acc = v < acc ? v : acc;
            else             acc = v > acc ? v : acc;
        }
        part[chunk][c] = acc;
    }
    __syncthreads();
    if (t < 100) {
        int a = t / 20;
        int acc = part[0][t];
        #pragma unroll
        for (int i = 1; i < 10; i++) {
            int v = part[i][t];
            if (a == 0)      acc += v;
            else if (a <= 2) acc = v < acc ? v : acc;
            else             acc = v > acc ? v : acc;
        }
        st[t] = acc;
    }
    __syncthreads();
    if (t != 0) return;

    int* cnt = st;
    int* mnx = st + 20; int* mny = st + 40; int* mxx = st + 60; int* mxy = st + 80;
    int* nb  = ws + NODE_OFF;

    // np.unique -> sorted present ids; drop smallest present id
    int firstp = -1;
    for (int i = 0; i < K_CLS; i++) if (cnt[i] > 0) { firstp = i; break; }
    int order[K_CLS]; int nc = 0;
    for (int i = 0; i < K_CLS; i++)
        if (cnt[i] > 0 && i != firstp) order[nc++] = i;

    // stable insertion sort, descending by count
    for (int i = 1; i < nc; i++) {
        int key = order[i]; int j = i - 1;
        while (j >= 0 && cnt[order[j]] < cnt[key]) { order[j + 1] = order[j]; j--; }
        order[j + 1] = key;
    }

    int nsel = 0;
    for (int i = 0; i < nc && nsel < NB_ - 2; i++) {
        int b = order[i];
        if (cnt[b] > CNT_THRESH) {
            nb[nsel * 4 + 0] = mnx[b] >> 4;
            nb[nsel * 4 + 1] = mny[b] >> 4;
            nb[nsel * 4 + 2] = mxx[b] >> 4;
            nb[nsel * 4 + 3] = mxy[b] >> 4;
            nsel++;
        }
    }
    const int bb[5][4] = {
        {W_ / 4, H_ / 4, 3 * W_ / 4, 3 * H_ / 4},
        {0, 0, W_ / 3, H_},
        {0, 0, W_, H_ / 3},
        {2 * W_ / 3, 0, W_, H_},
        {0, 2 * H_ / 3, W_, H_}
    };
    for (int i = 0; nsel < NB_; i++, nsel++) {
        nb[nsel * 4 + 0] = bb[i][0];
        nb[nsel * 4 + 1] = bb[i][1];
        nb[nsel * 4 + 2] = bb[i][2];
        nb[nsel * 4 + 3] = bb[i][3];
    }
}

__global__ __launch_bounds__(OUT_TPB) void out_k(const float* __restrict__ feat,
                      const int* __restrict__ nb,
                      float* __restrict__ out) {
    int sn    = blockIdx.x / BLKS_PER_SN;                        // uniform per block, 0..23
    int rbase = (blockIdx.x % BLKS_PER_SN) * OUT_BLK_ELEMS + threadIdx.x * OUT_EPT;
    float* o  = out + 2050 + (size_t)sn * ELEMS_PER_SN + rbase;  // byte addr == 8 (mod 16)

    if (sn >= 20) {                       // s == 5 -> identity copy (same linear layout)
        const float* src = feat + (size_t)(sn - 20) * ELEMS_PER_SN + rbase;  // 16B aligned
        float4 a  = *(const float4*)(src);
        float4 b4 = *(const float4*)(src + 4);
        float2* po = (float2*)o;
        po[0] = make_float2(a.x, a.y);
        po[1] = make_float2(a.z, a.w);
        po[2] = make_float2(b4.x, b4.y);
        po[3] = make_float2(b4.z, b4.w);
        return;
    }

    int b  = sn % NB_;                   // reshape (4,5,..)->(5,4,..)
    int n  = sn / NB_;
    int x0 = nb[b * 4 + 0], y0 = nb[b * 4 + 1];
    int x1 = nb[b * 4 + 2], y1 = nb[b * 4 + 3];
    int iw = x1 - x0; if (iw < 1) iw = 1;
    int ih = y1 - y0; if (ih < 1) ih = 1;

    int c  = rbase / (H_ * W_);
    int r2 = rbase - c * (H_ * W_);
    int h  = r2 / W_;
    int w0 = r2 - h * W_;                // in {0,8,16,24,32}

    // half-pixel-center bilinear; scale>=1 so antialias inert, edge renorm == clamp.
    // CLAMP ORDER MATTERS (R1 bug): hi tap = unclamped lo + 1, THEN clamp.
    // For fx in (-0.5,0): floor=-1 -> lo=0, hi=0 (both taps col 0). Computing
    // hi from the CLAMPED lo gives hi=1 -> O(1) error at every crop edge.
    float fy  = (h + 0.5f) * (float)ih / (float)H_ - 0.5f;
    float flY = floorf(fy);
    float ty  = fy - flY;
    int ylo_u = (int)flY;                          // >= -1 (fy >= -0.4875)
    int ylo = max(ylo_u, 0);                       // ylo_u <= ih-1 always
    int yhi = min(ylo_u + 1, ih - 1);              // ylo_u+1 >= 0
    int base = (n * C_ + c) * (H_ * W_) + x0;
    int r0i  = base + (y0 + ylo) * W_;
    int r1i  = base + (y0 + yhi) * W_;

    float sx = (float)iw * (1.0f / (float)W_);   // hoisted reciprocal (~1ulp vs /40)
    float wc = (float)w0 + 0.5f;
    float res[OUT_EPT];
    #pragma unroll
    for (int i = 0; i < OUT_EPT; i++) {
        float fx  = (wc + (float)i) * sx - 0.5f;
        float flX = floorf(fx);
        float tx  = fx - flX;
        int xlo_u = (int)flX;                      // >= -1
        int xlo = max(xlo_u, 0);                   // xlo_u <= iw-1 always
        int xhi = min(xlo_u + 1, iw - 1);          // from UNCLAMPED lo
        float v00 = feat[r0i + xlo], v01 = feat[r0i + xhi];
        float v10 = feat[r1i + xlo], v11 = feat[r1i + xhi];
        float top = v00 + tx * (v01 - v00);      // 3-FMA lerp, ~1ulp vs weighted form
        float bot = v10 + tx * (v11 - v10);
        res[i] = top + ty * (bot - top);
    }
    float2* po = (float2*)o;
    #pragma unroll
    for (int i = 0; i < 4; i++) po[i] = make_float2(res[2 * i], res[2 * i + 1]);
}

extern "C" void kernel_launch(void* const* d_in, const int* in_sizes, int n_in,
                              void* d_out, int out_size, void* d_ws, size_t ws_size,
                              hipStream_t stream) {
    const float* seg    = (const float*)d_in[0];
    const float* feat   = (const float*)d_in[1];
    const float* pool_x = (const float*)d_in[2];
    float* out = (float*)d_out;
    int* ws = (int*)d_ws;

    stats_k<<<NBLK_STATS, 256, 0, stream>>>(seg, ws);
    plan_k<<<1, 1024, 0, stream>>>(ws, pool_x, out);
    out_k<<<OUT_BLOCKS, OUT_TPB, 0, stream>>>(feat, ws + NODE_OFF, out);
}

// Round 3
// 203.330 us; speedup vs baseline: 1.2016x; 1.2016x over previous
//
#include <hip/hip_runtime.h>
#include <hip/hip_bf16.h>

#define K_CLS 20
#define HIN 480
#define WIN 640
#define NPIX (HIN * WIN)
#define C_ 512
#define H_ 30
#define W_ 40
#define HW_ (H_ * W_)
#define NB_ 5
#define CNT_THRESH 10000
// out layout (fp32): pool_x[2048], NB, N, x_cropped[6*4*512*30*40]
#define XCROP_ELEMS (6 * 4 * C_ * H_ * W_)
#define ELEMS_PER_SN (C_ * H_ * W_)            // 614400 = one (s,n) slice
#define OUT_TOTAL (2050 + XCROP_ELEMS)

#define NBLK_STATS 300                 // NPIX/4/256 exactly
#define NODE_OFF (NBLK_STATS * 100)    // ws int offset of the 5 node boxes

// out_k geometry (R3): block = one (sn, 8-channel group).
// All channels share identical bilinear tap indices/weights per (h,w), so
// taps are computed once per 8 outputs. Adjacent lanes = adjacent output
// columns -> tap loads per wave span <= iw+1 input columns (coalesced);
// stores are consecutive dwords (coalesced). R2's EPT=8-along-w had lanes
// 8 columns apart -> ~16 lines/wave-load -> transaction-bound (73.7us).
#define OUT_CPB 8                       // channels per block
#define OUT_CGRP (C_ / OUT_CPB)         // 64
#define OUT_TPB 256
#define OUT_BLOCKS (24 * OUT_CGRP)      // 1536

// ws int layout: [block][cnt20|mnx20|mny20|mxx20|mxy20] * 300, then boxes[5*4]

__global__ void stats_k(const float* __restrict__ seg, int* __restrict__ ws) {
    __shared__ int s_cnt[K_CLS], s_mnx[K_CLS], s_mny[K_CLS], s_mxx[K_CLS], s_mxy[K_CLS];
    int t = threadIdx.x;
    if (t < K_CLS) { s_cnt[t] = 0; s_mnx[t] = WIN; s_mny[t] = HIN; s_mxx[t] = -1; s_mxy[t] = -1; }
    __syncthreads();

    int p = blockIdx.x * blockDim.x + t;                 // quad-pixel index, 0..76799
    const float4* base = (const float4*)(seg + (size_t)3 * K_CLS * NPIX) + p;
    float4 v = base[0];
    float b0 = v.x, b1 = v.y, b2 = v.z, b3 = v.w;
    int k0 = 0, k1 = 0, k2 = 0, k3 = 0;
    #pragma unroll
    for (int k = 1; k < K_CLS; k++) {                    // strict > : np.argmax tie-break
        float4 u = base[(size_t)k * (NPIX / 4)];
        if (u.x > b0) { b0 = u.x; k0 = k; }
        if (u.y > b1) { b1 = u.y; k1 = k; }
        if (u.z > b2) { b2 = u.z; k2 = k; }
        if (u.w > b3) { b3 = u.w; k3 = k; }
    }
    int x = (p * 4) % WIN, y = (p * 4) / WIN;            // quad never wraps a row (640%4==0)
    if (k0 == k1 && k1 == k2 && k2 == k3) {              // common case: uniform class
        atomicAdd(&s_cnt[k0], 4);
        atomicMin(&s_mnx[k0], x);     atomicMax(&s_mxx[k0], x + 3);
        atomicMin(&s_mny[k0], y);     atomicMax(&s_mxy[k0], y);
    } else {
        int ks[4] = {k0, k1, k2, k3};
        #pragma unroll
        for (int i = 0; i < 4; i++) {
            atomicAdd(&s_cnt[ks[i]], 1);
            atomicMin(&s_mnx[ks[i]], x + i);  atomicMax(&s_mxx[ks[i]], x + i);
            atomicMin(&s_mny[ks[i]], y);      atomicMax(&s_mxy[ks[i]], y);
        }
    }
    __syncthreads();
    if (t < 100) {                                       // per-block partial, plain store
        int a = t / 20, c = t % 20;
        int val = (a == 0) ? s_cnt[c] : (a == 1) ? s_mnx[c] : (a == 2) ? s_mny[c]
                : (a == 3) ? s_mxx[c] : s_mxy[c];
        ws[blockIdx.x * 100 + t] = val;
    }
}

// Parallel reduce 300 partial records -> final stats -> boxes.
// Also copies the 2050-float header (pool_x, NB, N) so out_k's mapping
// is purely the x_cropped region (no per-thread header branch).
__global__ void plan_k(int* __restrict__ ws, const float* __restrict__ pool_x,
                       float* __restrict__ out) {
    __shared__ int part[10][100];
    __shared__ int st[100];
    int t = threadIdx.x;                 // 0..1023

    // header: 2048 floats of pool_x as 1024 float2, then {NB, N}
    ((float2*)out)[t] = ((const float2*)pool_x)[t];
    if (t == 0) { out[2048] = 5.0f; out[2049] = 4.0f; }

    if (t < 1000) {
        int c = t % 100, chunk = t / 100;
        int a = c / 20;
        int acc = (a == 0) ? 0 : (a == 1) ? WIN : (a == 2) ? HIN : -1;
        #pragma unroll
        for (int i = 0; i < 30; i++) {
            int v = ws[(chunk * 30 + i) * 100 + c];
            if (a == 0)      acc += v;
            else if (a <= 2) acc = v < acc ? v : acc;
            else             acc = v > acc ? v : acc;
        }
        part[chunk][c] = acc;
    }
    __syncthreads();
    if (t < 100) {
        int a = t / 20;
        int acc = part[0][t];
        #pragma unroll
        for (int i = 1; i < 10; i++) {
            int v = part[i][t];
            if (a == 0)      acc += v;
            else if (a <= 2) acc = v < acc ? v : acc;
            else             acc = v > acc ? v : acc;
        }
        st[t] = acc;
    }
    __syncthreads();
    if (t != 0) return;

    int* cnt = st;
    int* mnx = st + 20; int* mny = st + 40; int* mxx = st + 60; int* mxy = st + 80;
    int* nb  = ws + NODE_OFF;

    // np.unique -> sorted present ids; drop smallest present id
    int firstp = -1;
    for (int i = 0; i < K_CLS; i++) if (cnt[i] > 0) { firstp = i; break; }
    int order[K_CLS]; int nc = 0;
    for (int i = 0; i < K_CLS; i++)
        if (cnt[i] > 0 && i != firstp) order[nc++] = i;

    // stable insertion sort, descending by count
    for (int i = 1; i < nc; i++) {
        int key = order[i]; int j = i - 1;
        while (j >= 0 && cnt[order[j]] < cnt[key]) { order[j + 1] = order[j]; j--; }
        order[j + 1] = key;
    }

    int nsel = 0;
    for (int i = 0; i < nc && nsel < NB_ - 2; i++) {
        int b = order[i];
        if (cnt[b] > CNT_THRESH) {
            nb[nsel * 4 + 0] = mnx[b] >> 4;
            nb[nsel * 4 + 1] = mny[b] >> 4;
            nb[nsel * 4 + 2] = mxx[b] >> 4;
            nb[nsel * 4 + 3] = mxy[b] >> 4;
            nsel++;
        }
    }
    const int bb[5][4] = {
        {W_ / 4, H_ / 4, 3 * W_ / 4, 3 * H_ / 4},
        {0, 0, W_ / 3, H_},
        {0, 0, W_, H_ / 3},
        {2 * W_ / 3, 0, W_, H_},
        {0, 2 * H_ / 3, W_, H_}
    };
    for (int i = 0; nsel < NB_; i++, nsel++) {
        nb[nsel * 4 + 0] = bb[i][0];
        nb[nsel * 4 + 1] = bb[i][1];
        nb[nsel * 4 + 2] = bb[i][2];
        nb[nsel * 4 + 3] = bb[i][3];
    }
}

__global__ __launch_bounds__(OUT_TPB) void out_k(const float* __restrict__ feat,
                      const int* __restrict__ nb,
                      float* __restrict__ out) {
    int sn = blockIdx.x / OUT_CGRP;                      // uniform per block, 0..23
    int c0 = (blockIdx.x % OUT_CGRP) * OUT_CPB;          // channel group base
    float* obase = out + 2050 + (size_t)sn * ELEMS_PER_SN + (size_t)c0 * HW_;

    if (sn >= 20) {                      // s == 5 -> identity copy (same linear layout)
        const float* src = feat + ((size_t)(sn - 20) * C_ + c0) * HW_;
        // 9600 contiguous floats; dest is 8B-aligned (2050 % 4 == 2) -> float2
        for (int i = threadIdx.x; i < (OUT_CPB * HW_) / 2; i += OUT_TPB) {
            ((float2*)obase)[i] = ((const float2*)src)[i];
        }
        return;
    }

    int b  = sn % NB_;                   // flat (4,5)->(5,4) reshape: n=sn/5, b=sn%5
    int n  = sn / NB_;
    int x0 = nb[b * 4 + 0], y0 = nb[b * 4 + 1];
    int x1 = nb[b * 4 + 2], y1 = nb[b * 4 + 3];
    int iw = x1 - x0; if (iw < 1) iw = 1;
    int ih = y1 - y0; if (ih < 1) ih = 1;

    const float* src = feat + ((size_t)n * C_ + c0) * HW_ + (size_t)y0 * W_ + x0;
    float sx = (float)iw * (1.0f / (float)W_);
    float sy = (float)ih * (1.0f / (float)H_);

    for (int hw = threadIdx.x; hw < HW_; hw += OUT_TPB) {
        int h = hw / W_;
        int w = hw - h * W_;

        // half-pixel-center bilinear; scale<=1 here (iw<=40, ih<=30) so
        // antialias inert, edge renorm == clamp.
        // CLAMP ORDER (R1 bug): hi tap = unclamped lo + 1, THEN clamp.
        // fx,fy >= -0.5 -> lo_u >= -1, lo_u <= dim-1 always.
        float fy  = ((float)h + 0.5f) * sy - 0.5f;
        float flY = floorf(fy);
        float ty  = fy - flY;
        int ylo_u = (int)flY;
        int ylo = max(ylo_u, 0);
        int yhi = min(ylo_u + 1, ih - 1);

        float fx  = ((float)w + 0.5f) * sx - 0.5f;
        float flX = floorf(fx);
        float tx  = fx - flX;
        int xlo_u = (int)flX;
        int xlo = max(xlo_u, 0);
        int xhi = min(xlo_u + 1, iw - 1);

        int i00 = ylo * W_ + xlo, i01 = ylo * W_ + xhi;
        int i10 = yhi * W_ + xlo, i11 = yhi * W_ + xhi;

        const float* sp = src;
        float*       op = obase + hw;
        #pragma unroll
        for (int j = 0; j < OUT_CPB; j++) {              // taps shared by all channels
            float v00 = sp[i00], v01 = sp[i01];
            float v10 = sp[i10], v11 = sp[i11];
            float top = v00 + tx * (v01 - v00);          // 3-FMA lerp
            float bot = v10 + tx * (v11 - v10);
            *op = top + ty * (bot - top);
            sp += HW_; op += HW_;
        }
    }
}

extern "C" void kernel_launch(void* const* d_in, const int* in_sizes, int n_in,
                              void* d_out, int out_size, void* d_ws, size_t ws_size,
                              hipStream_t stream) {
    const float* seg    = (const float*)d_in[0];
    const float* feat   = (const float*)d_in[1];
    const float* pool_x = (const float*)d_in[2];
    float* out = (float*)d_out;
    int* ws = (int*)d_ws;

    stats_k<<<NBLK_STATS, 256, 0, stream>>>(seg, ws);
    plan_k<<<1, 1024, 0, stream>>>(ws, pool_x, out);
    out_k<<<OUT_BLOCKS, OUT_TPB, 0, stream>>>(feat, ws + NODE_OFF, out);
}

// Round 4
// 197.133 us; speedup vs baseline: 1.2394x; 1.0314x over previous
//
#include <hip/hip_runtime.h>
#include <hip/hip_bf16.h>

#define K_CLS 20
#define HIN 480
#define WIN 640
#define NPIX (HIN * WIN)
#define C_ 512
#define H_ 30
#define W_ 40
#define HW_ (H_ * W_)
#define NB_ 5
#define CNT_THRESH 10000
// out layout (fp32): pool_x[2048], NB, N, x_cropped[6*4*512*30*40]
#define XCROP_ELEMS (6 * 4 * C_ * H_ * W_)
#define ELEMS_PER_SN (C_ * H_ * W_)            // 614400 = one (s,n) slice
#define OUT_TOTAL (2050 + XCROP_ELEMS)

#define NBLK_STATS 300                 // NPIX/4/256 exactly
#define NODE_OFF (NBLK_STATS * 100)    // ws int offset of the 5 node boxes

// out_k geometry (R4): block = one (sn, 8-channel group), 38.4 KB of feat
// staged in LDS. R3 showed out_k ~33us vs a ~10.6us HBM floor with VALU
// 10.8% / HBM 12.3% -> bound on L1 gather transactions (32 scalar global
// gathers per thread-iter). Staging moves the gathers to LDS (lanes span
// <=41 consecutive dwords per tap = <=2 lanes/bank = conflict-free) and
// turns the global read into one coalesced float4 sweep.
#define OUT_CPB 8                       // channels per block
#define OUT_CGRP (C_ / OUT_CPB)         // 64
#define OUT_TPB 256
#define OUT_BLOCKS (24 * OUT_CGRP)      // 1536

// ws int layout: [block][cnt20|mnx20|mny20|mxx20|mxy20] * 300, then boxes[5*4]

__global__ void stats_k(const float* __restrict__ seg, int* __restrict__ ws) {
    __shared__ int s_cnt[K_CLS], s_mnx[K_CLS], s_mny[K_CLS], s_mxx[K_CLS], s_mxy[K_CLS];
    int t = threadIdx.x;
    if (t < K_CLS) { s_cnt[t] = 0; s_mnx[t] = WIN; s_mny[t] = HIN; s_mxx[t] = -1; s_mxy[t] = -1; }
    __syncthreads();

    int p = blockIdx.x * blockDim.x + t;                 // quad-pixel index, 0..76799
    const float4* base = (const float4*)(seg + (size_t)3 * K_CLS * NPIX) + p;
    float4 v = base[0];
    float b0 = v.x, b1 = v.y, b2 = v.z, b3 = v.w;
    int k0 = 0, k1 = 0, k2 = 0, k3 = 0;
    #pragma unroll
    for (int k = 1; k < K_CLS; k++) {                    // strict > : np.argmax tie-break
        float4 u = base[(size_t)k * (NPIX / 4)];
        if (u.x > b0) { b0 = u.x; k0 = k; }
        if (u.y > b1) { b1 = u.y; k1 = k; }
        if (u.z > b2) { b2 = u.z; k2 = k; }
        if (u.w > b3) { b3 = u.w; k3 = k; }
    }
    int x = (p * 4) % WIN, y = (p * 4) / WIN;            // quad never wraps a row (640%4==0)
    if (k0 == k1 && k1 == k2 && k2 == k3) {              // common case: uniform class
        atomicAdd(&s_cnt[k0], 4);
        atomicMin(&s_mnx[k0], x);     atomicMax(&s_mxx[k0], x + 3);
        atomicMin(&s_mny[k0], y);     atomicMax(&s_mxy[k0], y);
    } else {
        int ks[4] = {k0, k1, k2, k3};
        #pragma unroll
        for (int i = 0; i < 4; i++) {
            atomicAdd(&s_cnt[ks[i]], 1);
            atomicMin(&s_mnx[ks[i]], x + i);  atomicMax(&s_mxx[ks[i]], x + i);
            atomicMin(&s_mny[ks[i]], y);      atomicMax(&s_mxy[ks[i]], y);
        }
    }
    __syncthreads();
    if (t < 100) {                                       // per-block partial, plain store
        int a = t / 20, c = t % 20;
        int val = (a == 0) ? s_cnt[c] : (a == 1) ? s_mnx[c] : (a == 2) ? s_mny[c]
                : (a == 3) ? s_mxx[c] : s_mxy[c];
        ws[blockIdx.x * 100 + t] = val;
    }
}

// Parallel reduce 300 partial records -> final stats -> boxes.
// Also copies the 2050-float header (pool_x, NB, N) so out_k's mapping
// is purely the x_cropped region (no per-thread header branch).
__global__ void plan_k(int* __restrict__ ws, const float* __restrict__ pool_x,
                       float* __restrict__ out) {
    __shared__ int part[10][100];
    __shared__ int st[100];
    int t = threadIdx.x;                 // 0..1023

    // header: 2048 floats of pool_x as 1024 float2, then {NB, N}
    ((float2*)out)[t] = ((const float2*)pool_x)[t];
    if (t == 0) { out[2048] = 5.0f; out[2049] = 4.0f; }

    if (t < 1000) {
        int c = t % 100, chunk = t / 100;
        int a = c / 20;
        int acc = (a == 0) ? 0 : (a == 1) ? WIN : (a == 2) ? HIN : -1;
        #pragma unroll
        for (int i = 0; i < 30; i++) {
            int v = ws[(chunk * 30 + i) * 100 + c];
            if (a == 0)      acc += v;
            else if (a <= 2) acc = v < acc ? v : acc;
            else             acc = v > acc ? v : acc;
        }
        part[chunk][c] = acc;
    }
    __syncthreads();
    if (t < 100) {
        int a = t / 20;
        int acc = part[0][t];
        #pragma unroll
        for (int i = 1; i < 10; i++) {
            int v = part[i][t];
            if (a == 0)      acc += v;
            else if (a <= 2) acc = v < acc ? v : acc;
            else             acc = v > acc ? v : acc;
        }
        st[t] = acc;
    }
    __syncthreads();
    if (t != 0) return;

    int* cnt = st;
    int* mnx = st + 20; int* mny = st + 40; int* mxx = st + 60; int* mxy = st + 80;
    int* nb  = ws + NODE_OFF;

    // np.unique -> sorted present ids; drop smallest present id
    int firstp = -1;
    for (int i = 0; i < K_CLS; i++) if (cnt[i] > 0) { firstp = i; break; }
    int order[K_CLS]; int nc = 0;
    for (int i = 0; i < K_CLS; i++)
        if (cnt[i] > 0 && i != firstp) order[nc++] = i;

    // stable insertion sort, descending by count
    for (int i = 1; i < nc; i++) {
        int key = order[i]; int j = i - 1;
        while (j >= 0 && cnt[order[j]] < cnt[key]) { order[j + 1] = order[j]; j--; }
        order[j + 1] = key;
    }

    int nsel = 0;
    for (int i = 0; i < nc && nsel < NB_ - 2; i++) {
        int b = order[i];
        if (cnt[b] > CNT_THRESH) {
            nb[nsel * 4 + 0] = mnx[b] >> 4;
            nb[nsel * 4 + 1] = mny[b] >> 4;
            nb[nsel * 4 + 2] = mxx[b] >> 4;
            nb[nsel * 4 + 3] = mxy[b] >> 4;
            nsel++;
        }
    }
    const int bb[5][4] = {
        {W_ / 4, H_ / 4, 3 * W_ / 4, 3 * H_ / 4},
        {0, 0, W_ / 3, H_},
        {0, 0, W_, H_ / 3},
        {2 * W_ / 3, 0, W_, H_},
        {0, 2 * H_ / 3, W_, H_}
    };
    for (int i = 0; nsel < NB_; i++, nsel++) {
        nb[nsel * 4 + 0] = bb[i][0];
        nb[nsel * 4 + 1] = bb[i][1];
        nb[nsel * 4 + 2] = bb[i][2];
        nb[nsel * 4 + 3] = bb[i][3];
    }
}

__global__ __launch_bounds__(OUT_TPB) void out_k(const float* __restrict__ feat,
                      const int* __restrict__ nb,
                      float* __restrict__ out) {
    __shared__ float sf[OUT_CPB * HW_];                  // 38.4 KB feat slice
    int sn = blockIdx.x / OUT_CGRP;                      // uniform per block, 0..23
    int c0 = (blockIdx.x % OUT_CGRP) * OUT_CPB;          // channel group base
    float* obase = out + 2050 + (size_t)sn * ELEMS_PER_SN + (size_t)c0 * HW_;

    if (sn >= 20) {                      // s == 5 -> identity copy (same linear layout)
        const float* src = feat + ((size_t)(sn - 20) * C_ + c0) * HW_;
        // 9600 contiguous floats; dest is 8B-aligned (2050 % 4 == 2) -> float2
        for (int i = threadIdx.x; i < (OUT_CPB * HW_) / 2; i += OUT_TPB) {
            ((float2*)obase)[i] = ((const float2*)src)[i];
        }
        return;
    }

    int b  = sn % NB_;                   // flat (4,5)->(5,4) reshape: n=sn/5, b=sn%5
    int n  = sn / NB_;
    int x0 = nb[b * 4 + 0], y0 = nb[b * 4 + 1];
    int x1 = nb[b * 4 + 2], y1 = nb[b * 4 + 3];
    int iw = x1 - x0; if (iw < 1) iw = 1;
    int ih = y1 - y0; if (ih < 1) ih = 1;

    // stage this (n, c0..c0+7) slice into LDS, coalesced float4 sweep
    const float* src = feat + ((size_t)n * C_ + c0) * HW_;
    for (int i = threadIdx.x; i < (OUT_CPB * HW_) / 4; i += OUT_TPB) {
        ((float4*)sf)[i] = ((const float4*)src)[i];
    }
    __syncthreads();

    float sx = (float)iw * (1.0f / (float)W_);
    float sy = (float)ih * (1.0f / (float)H_);
    int cb = y0 * W_ + x0;               // crop base within one channel slice

    for (int hw = threadIdx.x; hw < HW_; hw += OUT_TPB) {
        int h = hw / W_;
        int w = hw - h * W_;

        // half-pixel-center bilinear; scale<=1 here (iw<=40, ih<=30) so
        // antialias inert, edge renorm == clamp.
        // CLAMP ORDER (R1 bug): hi tap = unclamped lo + 1, THEN clamp.
        // fx,fy >= -0.5 -> lo_u >= -1, lo_u <= dim-1 always.
        float fy  = ((float)h + 0.5f) * sy - 0.5f;
        float flY = floorf(fy);
        float ty  = fy - flY;
        int ylo_u = (int)flY;
        int ylo = max(ylo_u, 0);
        int yhi = min(ylo_u + 1, ih - 1);

        float fx  = ((float)w + 0.5f) * sx - 0.5f;
        float flX = floorf(fx);
        float tx  = fx - flX;
        int xlo_u = (int)flX;
        int xlo = max(xlo_u, 0);
        int xhi = min(xlo_u + 1, iw - 1);

        // indices within one channel slice; max (y1-1)*40 + x1-1 <= 1199
        int i00 = cb + ylo * W_ + xlo, i01 = cb + ylo * W_ + xhi;
        int i10 = cb + yhi * W_ + xlo, i11 = cb + yhi * W_ + xhi;

        float* op = obase + hw;
        #pragma unroll
        for (int j = 0; j < OUT_CPB; j++) {              // taps shared by all channels
            const float* sp = sf + j * HW_;              // j*4800B folds into ds imm
            float v00 = sp[i00], v01 = sp[i01];
            float v10 = sp[i10], v11 = sp[i11];
            float top = v00 + tx * (v01 - v00);          // 3-FMA lerp
            float bot = v10 + tx * (v11 - v10);
            op[j * HW_] = top + ty * (bot - top);
        }
    }
}

extern "C" void kernel_launch(void* const* d_in, const int* in_sizes, int n_in,
                              void* d_out, int out_size, void* d_ws, size_t ws_size,
                              hipStream_t stream) {
    const float* seg    = (const float*)d_in[0];
    const float* feat   = (const float*)d_in[1];
    const float* pool_x = (const float*)d_in[2];
    float* out = (float*)d_out;
    int* ws = (int*)d_ws;

    stats_k<<<NBLK_STATS, 256, 0, stream>>>(seg, ws);
    plan_k<<<1, 1024, 0, stream>>>(ws, pool_x, out);
    out_k<<<OUT_BLOCKS, OUT_TPB, 0, stream>>>(feat, ws + NODE_OFF, out);
}

// Round 6
// 196.861 us; speedup vs baseline: 1.2411x; 1.0014x over previous
//
#include <hip/hip_runtime.h>
#include <hip/hip_bf16.h>

#define K_CLS 20
#define HIN 480
#define WIN 640
#define NPIX (HIN * WIN)
#define C_ 512
#define H_ 30
#define W_ 40
#define HW_ (H_ * W_)
#define NB_ 5
#define CNT_THRESH 10000
// out layout (fp32): pool_x[2048], NB, N, x_cropped[6*4*512*30*40]
#define XCROP_ELEMS (6 * 4 * C_ * H_ * W_)
#define ELEMS_PER_SN (C_ * H_ * W_)            // 614400 = one (s,n) slice
#define OUT_TOTAL (2050 + XCROP_ELEMS)

#define NBLK_STATS 300                 // NPIX/4/256 exactly
#define NODE_OFF (NBLK_STATS * 100)    // ws int offset of the 5 node boxes

// native clang vector types: __builtin_nontemporal_store rejects
// HIP_vector_type (R5 compile fail) but accepts ext_vector_type.
typedef float f32x2 __attribute__((ext_vector_type(2)));
typedef float f32x4 __attribute__((ext_vector_type(4)));

// out_k geometry (R5/R6): block = one (sn, 4-channel group), 18.75 KB LDS.
// R4 (CPB=8, 38.4KB) capped residency at 4 blocks/CU (16 waves, 50% occ)
// and out_k sat at ~26.5us vs ~12-15us ideal-overlap budget -> theory:
// staging-barrier stalls + store latency not hidden. CPB=4 doubles
// resident blocks (8/CU, 32 waves = 100% occ) so one block's staging
// overlaps another's gather+store. Gather stays lane-stride-1
// (conflict-free); total LDS/store/staging traffic unchanged.
#define OUT_CPB 4                       // channels per block
#define OUT_CGRP (C_ / OUT_CPB)         // 128
#define OUT_TPB 256
#define OUT_BLOCKS (24 * OUT_CGRP)      // 3072

// ws int layout: [block][cnt20|mnx20|mny20|mxx20|mxy20] * 300, then boxes[5*4]

__global__ void stats_k(const float* __restrict__ seg, int* __restrict__ ws) {
    __shared__ int s_cnt[K_CLS], s_mnx[K_CLS], s_mny[K_CLS], s_mxx[K_CLS], s_mxy[K_CLS];
    int t = threadIdx.x;
    if (t < K_CLS) { s_cnt[t] = 0; s_mnx[t] = WIN; s_mny[t] = HIN; s_mxx[t] = -1; s_mxy[t] = -1; }
    __syncthreads();

    int p = blockIdx.x * blockDim.x + t;                 // quad-pixel index, 0..76799
    const float4* base = (const float4*)(seg + (size_t)3 * K_CLS * NPIX) + p;
    float4 v = base[0];
    float b0 = v.x, b1 = v.y, b2 = v.z, b3 = v.w;
    int k0 = 0, k1 = 0, k2 = 0, k3 = 0;
    #pragma unroll
    for (int k = 1; k < K_CLS; k++) {                    // strict > : np.argmax tie-break
        float4 u = base[(size_t)k * (NPIX / 4)];
        if (u.x > b0) { b0 = u.x; k0 = k; }
        if (u.y > b1) { b1 = u.y; k1 = k; }
        if (u.z > b2) { b2 = u.z; k2 = k; }
        if (u.w > b3) { b3 = u.w; k3 = k; }
    }
    int x = (p * 4) % WIN, y = (p * 4) / WIN;            // quad never wraps a row (640%4==0)
    if (k0 == k1 && k1 == k2 && k2 == k3) {              // common case: uniform class
        atomicAdd(&s_cnt[k0], 4);
        atomicMin(&s_mnx[k0], x);     atomicMax(&s_mxx[k0], x + 3);
        atomicMin(&s_mny[k0], y);     atomicMax(&s_mxy[k0], y);
    } else {
        int ks[4] = {k0, k1, k2, k3};
        #pragma unroll
        for (int i = 0; i < 4; i++) {
            atomicAdd(&s_cnt[ks[i]], 1);
            atomicMin(&s_mnx[ks[i]], x + i);  atomicMax(&s_mxx[ks[i]], x + i);
            atomicMin(&s_mny[ks[i]], y);      atomicMax(&s_mxy[ks[i]], y);
        }
    }
    __syncthreads();
    if (t < 100) {                                       // per-block partial, plain store
        int a = t / 20, c = t % 20;
        int val = (a == 0) ? s_cnt[c] : (a == 1) ? s_mnx[c] : (a == 2) ? s_mny[c]
                : (a == 3) ? s_mxx[c] : s_mxy[c];
        ws[blockIdx.x * 100 + t] = val;
    }
}

// Parallel reduce 300 partial records -> final stats -> boxes.
// Also copies the 2050-float header (pool_x, NB, N) so out_k's mapping
// is purely the x_cropped region (no per-thread header branch).
__global__ void plan_k(int* __restrict__ ws, const float* __restrict__ pool_x,
                       float* __restrict__ out) {
    __shared__ int part[10][100];
    __shared__ int st[100];
    int t = threadIdx.x;                 // 0..1023

    // header: 2048 floats of pool_x as 1024 float2, then {NB, N}
    ((float2*)out)[t] = ((const float2*)pool_x)[t];
    if (t == 0) { out[2048] = 5.0f; out[2049] = 4.0f; }

    if (t < 1000) {
        int c = t % 100, chunk = t / 100;
        int a = c / 20;
        int acc = (a == 0) ? 0 : (a == 1) ? WIN : (a == 2) ? HIN : -1;
        #pragma unroll
        for (int i = 0; i < 30; i++) {
            int v = ws[(chunk * 30 + i) * 100 + c];
            if (a == 0)      acc += v;
            else if (a <= 2) acc = v < acc ? v : acc;
            else             acc = v > acc ? v : acc;
        }
        part[chunk][c] = acc;
    }
    __syncthreads();
    if (t < 100) {
        int a = t / 20;
        int acc = part[0][t];
        #pragma unroll
        for (int i = 1; i < 10; i++) {
            int v = part[i][t];
            if (a == 0)      acc += v;
            else if (a <= 2) acc = v < acc ? v : acc;
            else             acc = v > acc ? v : acc;
        }
        st[t] = acc;
    }
    __syncthreads();
    if (t != 0) return;

    int* cnt = st;
    int* mnx = st + 20; int* mny = st + 40; int* mxx = st + 60; int* mxy = st + 80;
    int* nb  = ws + NODE_OFF;

    // np.unique -> sorted present ids; drop smallest present id
    int firstp = -1;
    for (int i = 0; i < K_CLS; i++) if (cnt[i] > 0) { firstp = i; break; }
    int order[K_CLS]; int nc = 0;
    for (int i = 0; i < K_CLS; i++)
        if (cnt[i] > 0 && i != firstp) order[nc++] = i;

    // stable insertion sort, descending by count
    for (int i = 1; i < nc; i++) {
        int key = order[i]; int j = i - 1;
        while (j >= 0 && cnt[order[j]] < cnt[key]) { order[j + 1] = order[j]; j--; }
        order[j + 1] = key;
    }

    int nsel = 0;
    for (int i = 0; i < nc && nsel < NB_ - 2; i++) {
        int b = order[i];
        if (cnt[b] > CNT_THRESH) {
            nb[nsel * 4 + 0] = mnx[b] >> 4;
            nb[nsel * 4 + 1] = mny[b] >> 4;
            nb[nsel * 4 + 2] = mxx[b] >> 4;
            nb[nsel * 4 + 3] = mxy[b] >> 4;
            nsel++;
        }
    }
    const int bb[5][4] = {
        {W_ / 4, H_ / 4, 3 * W_ / 4, 3 * H_ / 4},
        {0, 0, W_ / 3, H_},
        {0, 0, W_, H_ / 3},
        {2 * W_ / 3, 0, W_, H_},
        {0, 2 * H_ / 3, W_, H_}
    };
    for (int i = 0; nsel < NB_; i++, nsel++) {
        nb[nsel * 4 + 0] = bb[i][0];
        nb[nsel * 4 + 1] = bb[i][1];
        nb[nsel * 4 + 2] = bb[i][2];
        nb[nsel * 4 + 3] = bb[i][3];
    }
}

__global__ __launch_bounds__(OUT_TPB) void out_k(const float* __restrict__ feat,
                      const int* __restrict__ nb,
                      float* __restrict__ out) {
    __shared__ float sf[OUT_CPB * HW_];                  // 18.75 KB feat slice
    int sn = blockIdx.x / OUT_CGRP;                      // uniform per block, 0..23
    int c0 = (blockIdx.x % OUT_CGRP) * OUT_CPB;          // channel group base
    float* obase = out + 2050 + (size_t)sn * ELEMS_PER_SN + (size_t)c0 * HW_;

    if (sn >= 20) {                      // s == 5 -> identity copy (same linear layout)
        const float* src = feat + ((size_t)(sn - 20) * C_ + c0) * HW_;
        // 4800 contiguous floats; dest is 8B-aligned (2050 % 4 == 2) -> f32x2
        for (int i = threadIdx.x; i < (OUT_CPB * HW_) / 2; i += OUT_TPB) {
            __builtin_nontemporal_store(((const f32x2*)src)[i], (f32x2*)obase + i);
        }
        return;
    }

    int b  = sn % NB_;                   // flat (4,5)->(5,4) reshape: n=sn/5, b=sn%5
    int n  = sn / NB_;
    int x0 = nb[b * 4 + 0], y0 = nb[b * 4 + 1];
    int x1 = nb[b * 4 + 2], y1 = nb[b * 4 + 3];
    int iw = x1 - x0; if (iw < 1) iw = 1;
    int ih = y1 - y0; if (ih < 1) ih = 1;

    // stage this (n, c0..c0+3) slice into LDS, coalesced float4 sweep
    const float* src = feat + ((size_t)n * C_ + c0) * HW_;
    for (int i = threadIdx.x; i < (OUT_CPB * HW_) / 4; i += OUT_TPB) {
        ((f32x4*)sf)[i] = ((const f32x4*)src)[i];
    }
    __syncthreads();

    float sx = (float)iw * (1.0f / (float)W_);
    float sy = (float)ih * (1.0f / (float)H_);
    int cb = y0 * W_ + x0;               // crop base within one channel slice

    for (int hw = threadIdx.x; hw < HW_; hw += OUT_TPB) {
        int h = hw / W_;
        int w = hw - h * W_;

        // half-pixel-center bilinear; scale<=1 here (iw<=40, ih<=30) so
        // antialias inert, edge renorm == clamp.
        // CLAMP ORDER (R1 bug): hi tap = unclamped lo + 1, THEN clamp.
        // fx,fy >= -0.5 -> lo_u >= -1, lo_u <= dim-1 always.
        float fy  = ((float)h + 0.5f) * sy - 0.5f;
        float flY = floorf(fy);
        float ty  = fy - flY;
        int ylo_u = (int)flY;
        int ylo = max(ylo_u, 0);
        int yhi = min(ylo_u + 1, ih - 1);

        float fx  = ((float)w + 0.5f) * sx - 0.5f;
        float flX = floorf(fx);
        float tx  = fx - flX;
        int xlo_u = (int)flX;
        int xlo = max(xlo_u, 0);
        int xhi = min(xlo_u + 1, iw - 1);

        // indices within one channel slice; max (y1-1)*40 + x1-1 <= 1199
        int i00 = cb + ylo * W_ + xlo, i01 = cb + ylo * W_ + xhi;
        int i10 = cb + yhi * W_ + xlo, i11 = cb + yhi * W_ + xhi;

        float* op = obase + hw;
        #pragma unroll
        for (int j = 0; j < OUT_CPB; j++) {              // taps shared by all channels
            const float* sp = sf + j * HW_;              // j*4800B folds into ds imm
            float v00 = sp[i00], v01 = sp[i01];
            float v10 = sp[i10], v11 = sp[i11];
            float top = v00 + tx * (v01 - v00);          // 3-FMA lerp
            float bot = v10 + tx * (v11 - v10);
            __builtin_nontemporal_store(top + ty * (bot - top), op + j * HW_);
        }
    }
}

extern "C" void kernel_launch(void* const* d_in, const int* in_sizes, int n_in,
                              void* d_out, int out_size, void* d_ws, size_t ws_size,
                              hipStream_t stream) {
    const float* seg    = (const float*)d_in[0];
    const float* feat   = (const float*)d_in[1];
    const float* pool_x = (const float*)d_in[2];
    float* out = (float*)d_out;
    int* ws = (int*)d_ws;

    stats_k<<<NBLK_STATS, 256, 0, stream>>>(seg, ws);
    plan_k<<<1, 1024, 0, stream>>>(ws, pool_x, out);
    out_k<<<OUT_BLOCKS, OUT_TPB, 0, stream>>>(feat, ws + NODE_OFF, out);
}